// Round 3
// baseline (44.103 us; speedup 1.0000x reference)
//
#include <hip/hip_runtime.h>
#include <math.h>

#define NPTS   2048
#define BATCH  32
#define M_POLY 815
#define PSTRIDE 153      // 136 P12 pair products + 16 T0 + 1 pad
#define BN_EPS 1e-5f
#define TRI(j) ((j)*(33-(j))/2)

// ---------------------------------------------------------------------------
// Moments kernel. grid = (32/GPB, BATCH), block = 320 (5 waves).
// Closed-form monomial enumeration (matches combinations_with_replacement):
//   degree D=1..15; within D: c=e0 from D down to 0 (runs), within run:
//   e1 = (D-c)-e2, e2 ascending.  m = C(D+2,3)-1 + L(L+1)/2 + e2, L=D-c.
// Threads 0..258 each own one 4-chunk of one run: per point read T0[c] once
// (banks 8..23, conflict-free) + 4 P12 gathers + 4 FMA.
// Phase A: 4 waves build the 152-word table slices for 64 points.
// ---------------------------------------------------------------------------
template<int GPB>
__global__ __launch_bounds__(320, 4) void moments_kernel(
    const float* __restrict__ x,      // (B, 3, N)
    float*       __restrict__ part)   // (B, 32/GPB, M_POLY)
{
    __shared__ float P[64 * PSTRIDE];   // 39,168 B
    const int t  = threadIdx.x;
    const int sb = blockIdx.x;
    const int b  = blockIdx.y;

    // ---- chunk decode: thread -> (D, c, k0) ----
    int D = 0, c = -1, k0 = 0;
    {
        int q = t;
        for (int d = 1; d <= 15 && c < 0; ++d) {
            for (int cc = d; cc >= 0; --cc) {
                const int ncc = (d - cc + 4) >> 2;   // ceil((d-cc+1)/4)
                if (q < ncc) { D = d; c = cc; k0 = q << 2; break; }
                q -= ncc;
            }
        }
    }
    const int L    = (c >= 0) ? (D - c) : 0;
    const int offt = 136 + ((c >= 0) ? c : 0);
    int offp0, offp1, offp2, offp3, m0, m1, m2, m3;
    {
        const int mbase = (c >= 0) ? (((D + 2) * (D + 1) * D) / 6 - 1 + (L * (L + 1)) / 2) : -1;
        const int e2a = k0 + 0, e2b = k0 + 1, e2c_ = k0 + 2, e2d = k0 + 3;
        const bool va = (c >= 0) && (e2a <= L), vb = (c >= 0) && (e2b <= L);
        const bool vc = (c >= 0) && (e2c_ <= L), vd = (c >= 0) && (e2d <= L);
        const int ca = va ? e2a : L, cb = vb ? e2b : L, cc2 = vc ? e2c_ : L, cd = vd ? e2d : L;
        const int ea = L - ca, eb = L - cb, ec = L - cc2, ed = L - cd;
        offp0 = (ea * (33 - ea)) / 2 + ca;  m0 = va ? (mbase + e2a) : -1;
        offp1 = (eb * (33 - eb)) / 2 + cb;  m1 = vb ? (mbase + e2b) : -1;
        offp2 = (ec * (33 - ec)) / 2 + cc2; m2 = vc ? (mbase + e2c_) : -1;
        offp3 = (ed * (33 - ed)) / 2 + cd;  m3 = vd ? (mbase + e2d) : -1;
    }

    float a0 = 0.f, a1 = 0.f, a2 = 0.f, a3 = 0.f;
    const float* xb = x + (size_t)b * 3 * NPTS;

    for (int g = 0; g < GPB; ++g) {
        if (g) __syncthreads();
        if (t < 256) {
            const int nn = t & 63, qq = t >> 6;
            const int n  = (sb * GPB + g) * 64 + nn;
            const float x1 = xb[NPTS + n], x2 = xb[2 * NPTS + n];
            float* pt = &P[nn * PSTRIDE];
            float T2r[16];
            T2r[0] = 1.f; T2r[1] = x2;
            #pragma unroll
            for (int k = 2; k < 16; ++k) T2r[k] = 2.f * x2 * T2r[k - 1] - T2r[k - 2];
            // T1 orders as scalars (compiler keeps live ones per branch)
            const float u0 = 1.f, u1 = x1;
            const float u2 = 2.f*x1*u1-u0,  u3 = 2.f*x1*u2-u1,  u4 = 2.f*x1*u3-u2;
            const float u5 = 2.f*x1*u4-u3,  u6 = 2.f*x1*u5-u4,  u7 = 2.f*x1*u6-u5;
            const float u8 = 2.f*x1*u7-u6,  u9 = 2.f*x1*u8-u7,  u10 = 2.f*x1*u9-u8;
            const float u11 = 2.f*x1*u10-u9, u12 = 2.f*x1*u11-u10, u13 = 2.f*x1*u12-u11;
            const float u14 = 2.f*x1*u13-u12, u15 = 2.f*x1*u14-u13;
            #define ROWW(j, T1V) { _Pragma("unroll") \
                for (int k = 0; k < 16 - (j); ++k) pt[TRI(j) + k] = (T1V) * T2r[k]; }
            if (qq == 0)      { ROWW(0, u0)  ROWW(1, u1)  ROWW(2, u2) }
            else if (qq == 1) { ROWW(3, u3)  ROWW(4, u4)  ROWW(5, u5)  ROWW(6, u6) }
            else if (qq == 2) { ROWW(7, u7)  ROWW(8, u8)  ROWW(9, u9)  ROWW(10, u10) ROWW(11, u11) }
            else {
                ROWW(12, u12) ROWW(13, u13) ROWW(14, u14) ROWW(15, u15)
                const float x0 = xb[n];
                float vp = 1.f, vcur = x0;
                pt[136] = vp; pt[137] = vcur;
                #pragma unroll
                for (int k = 2; k < 16; ++k) {
                    const float vn = 2.f * x0 * vcur - vp;
                    pt[136 + k] = vn; vp = vcur; vcur = vn;
                }
            }
            #undef ROWW
        }
        __syncthreads();

        if (c >= 0) {
            const float* row = P;
            #pragma unroll 4
            for (int nn = 0; nn < 64; ++nn) {
                const float t0v = row[offt];
                a0 = fmaf(t0v, row[offp0], a0);
                a1 = fmaf(t0v, row[offp1], a1);
                a2 = fmaf(t0v, row[offp2], a2);
                a3 = fmaf(t0v, row[offp3], a3);
                row += PSTRIDE;
            }
        }
    }

    if (c >= 0) {
        float* pb = part + ((size_t)b * (32 / GPB) + sb) * M_POLY;
        if (m0 >= 0) pb[m0] = a0;
        if (m1 >= 0) pb[m1] = a1;
        if (m2 >= 0) pb[m2] = a2;
        if (m3 >= 0) pb[m3] = a3;
    }
}

// ---------------------------------------------------------------------------
// Layer 1: reduce partials + 815->512 + BN + ReLU.
// grid = (8, 32), block 1024 = 64 outputs x 16 k-groups (chains of 51).
// ---------------------------------------------------------------------------
__global__ __launch_bounds__(1024, 4) void l1_kernel(
    const float* __restrict__ part, int nsplit,
    const float* __restrict__ W1, const float* __restrict__ b1,
    const float* __restrict__ g1, const float* __restrict__ be1,
    const float* __restrict__ rm1, const float* __restrict__ rv1,
    float* __restrict__ h1)
{
    __shared__ float fs[816];
    __shared__ float red[16][64];
    const int t  = threadIdx.x;
    const int og = blockIdx.x;
    const int b  = blockIdx.y;

    if (t < 815) {
        float s = 0.f;
        #pragma unroll 4
        for (int sp = 0; sp < nsplit; ++sp)
            s += part[((size_t)b * nsplit + sp) * M_POLY + t];
        fs[t] = s * (1.0f / (float)NPTS);
    } else if (t == 815) {
        fs[815] = 0.f;
    }
    __syncthreads();

    const int o  = og * 64 + (t & 63);
    const int cg = t >> 6;
    const int kb = cg * 51;
    float acc = 0.f;
    #pragma unroll 8
    for (int kk = 0; kk < 51; ++kk) {
        const int k  = kb + kk;
        const int kr = (k < 815) ? k : 814;    // fs[815]=0 nulls the pad
        acc = fmaf(fs[k], W1[(size_t)kr * 512 + o], acc);
    }
    red[cg][t & 63] = acc;
    __syncthreads();

    if (t < 64) {
        float dot = 0.f;
        #pragma unroll
        for (int j = 0; j < 16; ++j) dot += red[j][t];
        const int oo = og * 64 + t;
        const float v = (dot + b1[oo] - rm1[oo]) * g1[oo] * rsqrtf(rv1[oo] + BN_EPS) + be1[oo];
        h1[b * 512 + oo] = v > 0.f ? v : 0.f;
    }
}

// ---------------------------------------------------------------------------
// Layer 2: 512->256 + BN + ReLU. grid (4, 32), block 1024 = 64 o x 16 kg.
// ---------------------------------------------------------------------------
__global__ __launch_bounds__(1024, 4) void l2_kernel(
    const float* __restrict__ h1,
    const float* __restrict__ W2, const float* __restrict__ b2,
    const float* __restrict__ g2, const float* __restrict__ be2,
    const float* __restrict__ rm2, const float* __restrict__ rv2,
    float* __restrict__ h2)
{
    __shared__ float hs[512];
    __shared__ float red[16][64];
    const int t  = threadIdx.x;
    const int og = blockIdx.x;
    const int b  = blockIdx.y;

    if (t < 512) hs[t] = h1[b * 512 + t];
    __syncthreads();

    const int o  = og * 64 + (t & 63);
    const int cg = t >> 6;
    const int kb = cg * 32;
    float acc = 0.f;
    #pragma unroll 8
    for (int kk = 0; kk < 32; ++kk) {
        const int k = kb + kk;
        acc = fmaf(hs[k], W2[(size_t)k * 256 + o], acc);
    }
    red[cg][t & 63] = acc;
    __syncthreads();

    if (t < 64) {
        float dot = 0.f;
        #pragma unroll
        for (int j = 0; j < 16; ++j) dot += red[j][t];
        const int oo = og * 64 + t;
        const float v = (dot + b2[oo] - rm2[oo]) * g2[oo] * rsqrtf(rv2[oo] + BN_EPS) + be2[oo];
        h2[b * 256 + oo] = v > 0.f ? v : 0.f;
    }
}

// ---------------------------------------------------------------------------
// Layers 3+4: 256->128 (BN+ReLU) -> 128->40. grid = 32, block 1024.
// ---------------------------------------------------------------------------
__global__ __launch_bounds__(1024, 4) void l34_kernel(
    const float* __restrict__ h2,
    const float* __restrict__ W3, const float* __restrict__ b3,
    const float* __restrict__ g3, const float* __restrict__ be3,
    const float* __restrict__ rm3, const float* __restrict__ rv3,
    const float* __restrict__ W4, const float* __restrict__ b4,
    float* __restrict__ out)
{
    __shared__ float hs[256];
    __shared__ float red3[8][128];
    __shared__ float h3s[128];
    __shared__ float red4[16][64];
    const int t = threadIdx.x;
    const int b = blockIdx.x;

    if (t < 256) hs[t] = h2[b * 256 + t];
    __syncthreads();

    // L3: 128 outputs x 8 k-groups (chains of 32)
    {
        const int o  = t & 127;
        const int cg = t >> 7;
        const int kb = cg * 32;
        float acc = 0.f;
        #pragma unroll 8
        for (int kk = 0; kk < 32; ++kk) {
            const int k = kb + kk;
            acc = fmaf(hs[k], W3[(size_t)k * 128 + o], acc);
        }
        red3[cg][o] = acc;
    }
    __syncthreads();
    if (t < 128) {
        float dot = 0.f;
        #pragma unroll
        for (int j = 0; j < 8; ++j) dot += red3[j][t];
        const float v = (dot + b3[t] - rm3[t]) * g3[t] * rsqrtf(rv3[t] + BN_EPS) + be3[t];
        h3s[t] = v > 0.f ? v : 0.f;
    }
    __syncthreads();

    // L4: 40 outputs (o<64 lanes, clamp) x 16 k-groups (chains of 8)
    {
        const int o  = t & 63;
        const int om = (o < 40) ? o : 39;
        const int cg = t >> 6;
        const int kb = cg * 8;
        float acc = 0.f;
        #pragma unroll
        for (int kk = 0; kk < 8; ++kk) {
            const int k = kb + kk;
            acc = fmaf(h3s[k], W4[(size_t)k * 40 + om], acc);
        }
        red4[cg][o] = acc;
    }
    __syncthreads();
    if (t < 40) {
        float dot = 0.f;
        #pragma unroll
        for (int j = 0; j < 16; ++j) dot += red4[j][t];
        out[b * 40 + t] = dot + b4[t];
    }
}

extern "C" void kernel_launch(void* const* d_in, const int* in_sizes, int n_in,
                              void* d_out, int out_size, void* d_ws, size_t ws_size,
                              hipStream_t stream) {
    const float* x  = (const float*)d_in[0];
    const float* W1 = (const float*)d_in[2];
    const float* b1 = (const float*)d_in[3];
    const float* g1 = (const float*)d_in[4];
    const float* be1= (const float*)d_in[5];
    const float* rm1= (const float*)d_in[6];
    const float* rv1= (const float*)d_in[7];
    const float* W2 = (const float*)d_in[8];
    const float* b2 = (const float*)d_in[9];
    const float* g2 = (const float*)d_in[10];
    const float* be2= (const float*)d_in[11];
    const float* rm2= (const float*)d_in[12];
    const float* rv2= (const float*)d_in[13];
    const float* W3 = (const float*)d_in[14];
    const float* b3 = (const float*)d_in[15];
    const float* g3 = (const float*)d_in[16];
    const float* be3= (const float*)d_in[17];
    const float* rm3= (const float*)d_in[18];
    const float* rv3= (const float*)d_in[19];
    const float* W4 = (const float*)d_in[20];
    const float* b4 = (const float*)d_in[21];
    float* out = (float*)d_out;

    const size_t hElems = (size_t)BATCH * 512 + (size_t)BATCH * 256;
    int nsplit;
    if (ws_size >= ((size_t)BATCH * 16 * M_POLY + hElems) * 4) nsplit = 16;
    else                                                       nsplit = 8;

    float* part = (float*)d_ws;
    float* h1   = part + (size_t)BATCH * nsplit * M_POLY;
    float* h2   = h1 + (size_t)BATCH * 512;

    if (nsplit == 16)
        moments_kernel<2><<<dim3(16, BATCH), 320, 0, stream>>>(x, part);
    else
        moments_kernel<4><<<dim3(8, BATCH), 320, 0, stream>>>(x, part);

    l1_kernel<<<dim3(8, BATCH), 1024, 0, stream>>>(part, nsplit,
        W1, b1, g1, be1, rm1, rv1, h1);
    l2_kernel<<<dim3(4, BATCH), 1024, 0, stream>>>(h1,
        W2, b2, g2, be2, rm2, rv2, h2);
    l34_kernel<<<BATCH, 1024, 0, stream>>>(h2,
        W3, b3, g3, be3, rm3, rv3, W4, b4, out);
}

// Round 4
// 33.363 us; speedup vs baseline: 1.3219x; 1.3219x over previous
//
#include <hip/hip_runtime.h>
#include <math.h>

#define NPTS   2048
#define BATCH  32
#define M_POLY 815
#define GPB    2
#define NSPLIT 16            // 2048 / (64*GPB)
#define RSTR   192           // words per point row (6 x 32-word frames)
#define BN_EPS 1e-5f

// Logical per-point row (192 words):
//   [0,16)   T0[c] = T_c(x0)          [16,32) pad (never read)
//   [32,192) Q rows s=0..15 at 32+QOFF(s): Q[s][e2] = T1[s-e2]*T2[e2],
//            each row padded to 4-word blocks (QOFF: 0,4,8,12,16,24,32,40,
//            48,60,72,84,96,112,128,144; total 160 words)
// Physical word = logical ^ sw,  sw = 4*(nn&7)  (XOR permutes 4-word blocks
// within each 32-word frame -> b128 alignment preserved, phase-A writes
// spread over all 8 bank-quads, phase-B reads recover via same XOR).

// chunk ci -> (L=e1+e2, k0 = e2 block start, c=e0, qoff4 = logical word of Q block)
// ordering: L-major, then k0, then c  => wave-mates share the b128 address.
__device__ __forceinline__ bool decode_chunk(int ci, int& Lo, int& k0o, int& co, int& qo) {
    int idx = 0, qoff = 0;
    for (int l = 0; l < 16; ++l) {
        const int nb   = (l + 4) >> 2;          // blocks of 4 e2-values
        const int cmin = (l == 0) ? 1 : 0;      // drop the constant monomial
        const int nc   = 16 - l - cmin;         // c in [cmin, 15-l]
        for (int kb = 0; kb < nb; ++kb) {
            if (ci < idx + nc) {
                Lo = l; k0o = kb * 4; co = cmin + (ci - idx);
                qo = 32 + qoff + kb * 4;
                return true;
            }
            idx += nc;
        }
        qoff += nb * 4;
    }
    return false;
}

__global__ __launch_bounds__(256) void moments_kernel(
    const float* __restrict__ x,      // (B, 3, N)
    float*       __restrict__ part)   // (B, NSPLIT, M_POLY)
{
    __shared__ __align__(16) float P[64 * RSTR];   // 49,152 B
    const int t  = threadIdx.x;
    const int sb = blockIdx.x;
    const int b  = blockIdx.y;
    const int nn = t & 63;
    const int qq = t >> 6;
    const int sw = 4 * (nn & 7);
    const int base = nn * RSTR;

    // ---- chunk decode (all t<256 valid; lanes 61..63 carry chunks 256..258) ----
    int L, k0, c, qoff4;
    decode_chunk(t, L, k0, c, qoff4);
    const bool dual = (t >= 61 && t <= 63);
    int L2 = 0, k02 = 0, c2 = 0, qoff42 = 32;
    if (dual) decode_chunk(256 + (t - 61), L2, k02, c2, qoff42);

    int qx[8], tx[8], q2x[8], t2x[8];
    #pragma unroll
    for (int r = 0; r < 8; ++r) {
        qx[r]  = qoff4  ^ (4 * r);
        tx[r]  = c      ^ (4 * r);
        q2x[r] = qoff42 ^ (4 * r);
        t2x[r] = c2     ^ (4 * r);
    }

    float a[4]  = {0.f, 0.f, 0.f, 0.f};
    float a2[4] = {0.f, 0.f, 0.f, 0.f};
    const float* xb = x + (size_t)b * 3 * NPTS;

    for (int g = 0; g < GPB; ++g) {
        if (g) __syncthreads();
        // ---------------- phase A: build swizzled tables ----------------
        {
            const int n = (sb * GPB + g) * 64 + nn;
            const float x1 = xb[NPTS + n], x2 = xb[2 * NPTS + n];
            float T1r[16], T2r[16];
            T1r[0] = 1.f; T1r[1] = x1;
            #pragma unroll
            for (int k = 2; k < 16; ++k) T1r[k] = 2.f * x1 * T1r[k-1] - T1r[k-2];
            T2r[0] = 1.f; T2r[1] = x2;
            #pragma unroll
            for (int k = 2; k < 16; ++k) T2r[k] = 2.f * x2 * T2r[k-1] - T2r[k-2];

            #define QVAL(S,E) (((E) <= (S)) ? T1r[((S)-(E)) & 15] * T2r[(E) & 15] : 0.f)
            #define ROWQ(S, QO) { \
                _Pragma("unroll") \
                for (int blk = 0; blk < ((S)+4)/4; ++blk) { \
                    float4 v; \
                    v.x = QVAL(S, 4*blk+0); v.y = QVAL(S, 4*blk+1); \
                    v.z = QVAL(S, 4*blk+2); v.w = QVAL(S, 4*blk+3); \
                    *(float4*)&P[base + ((32 + (QO) + 4*blk) ^ sw)] = v; } }

            if (qq == 0) {
                const float x0 = xb[n];
                float T0r[16];
                T0r[0] = 1.f; T0r[1] = x0;
                #pragma unroll
                for (int k = 2; k < 16; ++k) T0r[k] = 2.f * x0 * T0r[k-1] - T0r[k-2];
                #pragma unroll
                for (int blk = 0; blk < 8; ++blk) {
                    float4 v;
                    v.x = (4*blk+0 < 16) ? T0r[(4*blk+0) & 15] : 0.f;
                    v.y = (4*blk+1 < 16) ? T0r[(4*blk+1) & 15] : 0.f;
                    v.z = (4*blk+2 < 16) ? T0r[(4*blk+2) & 15] : 0.f;
                    v.w = (4*blk+3 < 16) ? T0r[(4*blk+3) & 15] : 0.f;
                    *(float4*)&P[base + ((4*blk) ^ sw)] = v;
                }
                ROWQ(0, 0)  ROWQ(1, 4)  ROWQ(2, 8)  ROWQ(3, 12)
            } else if (qq == 1) {
                ROWQ(4, 16) ROWQ(5, 24) ROWQ(6, 32) ROWQ(7, 40) ROWQ(8, 48)
            } else if (qq == 2) {
                ROWQ(9, 60) ROWQ(10, 72) ROWQ(11, 84) ROWQ(12, 96)
            } else {
                ROWQ(13, 112) ROWQ(14, 128) ROWQ(15, 144)
            }
            #undef ROWQ
            #undef QVAL
        }
        __syncthreads();

        // ---------------- phase B: accumulate ----------------
        for (int n8 = 0; n8 < 8; ++n8) {
            const float* rp0 = &P[n8 * 8 * RSTR];
            #pragma unroll
            for (int r = 0; r < 8; ++r) {
                const float* rp = rp0 + r * RSTR;   // point nn = n8*8+r, sw = 4*r
                const float t0v = rp[tx[r]];
                const float4 q = *(const float4*)&rp[qx[r]];
                a[0] = fmaf(t0v, q.x, a[0]);
                a[1] = fmaf(t0v, q.y, a[1]);
                a[2] = fmaf(t0v, q.z, a[2]);
                a[3] = fmaf(t0v, q.w, a[3]);
                if (dual) {
                    const float u0 = rp[t2x[r]];
                    const float4 p2 = *(const float4*)&rp[q2x[r]];
                    a2[0] = fmaf(u0, p2.x, a2[0]);
                    a2[1] = fmaf(u0, p2.y, a2[1]);
                    a2[2] = fmaf(u0, p2.z, a2[2]);
                    a2[3] = fmaf(u0, p2.w, a2[3]);
                }
            }
        }
    }

    // ---- store partials: m = tet(D)-1 + L(L+1)/2 + e2, consecutive in e2 ----
    float* pb = part + ((size_t)b * NSPLIT + sb) * M_POLY;
    {
        const int D  = c + L;
        const int mb = D * (D + 1) * (D + 2) / 6 - 1 + L * (L + 1) / 2;
        const int nv = (L - k0 + 1 < 4) ? (L - k0 + 1) : 4;
        #pragma unroll
        for (int i = 0; i < 4; ++i)
            if (i < nv) pb[mb + k0 + i] = a[i];
    }
    if (dual) {
        const int D  = c2 + L2;
        const int mb = D * (D + 1) * (D + 2) / 6 - 1 + L2 * (L2 + 1) / 2;
        const int nv = (L2 - k02 + 1 < 4) ? (L2 - k02 + 1) : 4;
        #pragma unroll
        for (int i = 0; i < 4; ++i)
            if (i < nv) pb[mb + k02 + i] = a2[i];
    }
}

// ---------------------------------------------------------------------------
// Layer 1: reduce partials + 815->512 + BN + ReLU.
// grid = (16, 32), block 512 = 32 outputs x 16 k-groups (chains of 51).
// ---------------------------------------------------------------------------
__global__ __launch_bounds__(512) void l1_kernel(
    const float* __restrict__ part,
    const float* __restrict__ W1, const float* __restrict__ b1,
    const float* __restrict__ g1, const float* __restrict__ be1,
    const float* __restrict__ rm1, const float* __restrict__ rv1,
    float* __restrict__ h1)
{
    __shared__ float fs[816];
    __shared__ float red[16][32];
    const int t  = threadIdx.x;
    const int og = blockIdx.x;
    const int b  = blockIdx.y;

    {
        float s0 = 0.f;
        #pragma unroll
        for (int sp = 0; sp < NSPLIT; ++sp)
            s0 += part[((size_t)b * NSPLIT + sp) * M_POLY + t];
        fs[t] = s0 * (1.0f / (float)NPTS);
        if (t < 303) {
            float s1 = 0.f;
            #pragma unroll
            for (int sp = 0; sp < NSPLIT; ++sp)
                s1 += part[((size_t)b * NSPLIT + sp) * M_POLY + 512 + t];
            fs[512 + t] = s1 * (1.0f / (float)NPTS);
        }
        if (t == 0) fs[815] = 0.f;
    }
    __syncthreads();

    const int o  = og * 32 + (t & 31);
    const int cg = t >> 5;
    const int kb = cg * 51;                 // 16*51 = 816; fs[815]=0 nulls pad
    float acc = 0.f;
    #pragma unroll 8
    for (int kk = 0; kk < 51; ++kk) {
        const int k  = kb + kk;
        const int kr = (k < 815) ? k : 814;
        acc = fmaf(fs[k], W1[(size_t)kr * 512 + o], acc);
    }
    red[cg][t & 31] = acc;
    __syncthreads();

    if (t < 32) {
        float dot = 0.f;
        #pragma unroll
        for (int j = 0; j < 16; ++j) dot += red[j][t];
        const int oo = og * 32 + t;
        const float v = (dot + b1[oo] - rm1[oo]) * g1[oo] * rsqrtf(rv1[oo] + BN_EPS) + be1[oo];
        h1[b * 512 + oo] = v > 0.f ? v : 0.f;
    }
}

// ---------------------------------------------------------------------------
// Layer 2: 512->256 + BN + ReLU. grid (8, 32), block 512 = 32 o x 16 kg.
// ---------------------------------------------------------------------------
__global__ __launch_bounds__(512) void l2_kernel(
    const float* __restrict__ h1,
    const float* __restrict__ W2, const float* __restrict__ b2,
    const float* __restrict__ g2, const float* __restrict__ be2,
    const float* __restrict__ rm2, const float* __restrict__ rv2,
    float* __restrict__ h2)
{
    __shared__ float hs[512];
    __shared__ float red[16][32];
    const int t  = threadIdx.x;
    const int og = blockIdx.x;
    const int b  = blockIdx.y;

    hs[t] = h1[b * 512 + t];
    __syncthreads();

    const int o  = og * 32 + (t & 31);
    const int cg = t >> 5;
    const int kb = cg * 32;
    float acc = 0.f;
    #pragma unroll
    for (int kk = 0; kk < 32; ++kk)
        acc = fmaf(hs[kb + kk], W2[(size_t)(kb + kk) * 256 + o], acc);
    red[cg][t & 31] = acc;
    __syncthreads();

    if (t < 32) {
        float dot = 0.f;
        #pragma unroll
        for (int j = 0; j < 16; ++j) dot += red[j][t];
        const int oo = og * 32 + t;
        const float v = (dot + b2[oo] - rm2[oo]) * g2[oo] * rsqrtf(rv2[oo] + BN_EPS) + be2[oo];
        h2[b * 256 + oo] = v > 0.f ? v : 0.f;
    }
}

// ---------------------------------------------------------------------------
// Layers 3+4: 256->128 (BN+ReLU) -> 128->40. grid = 32, block 512.
// ---------------------------------------------------------------------------
__global__ __launch_bounds__(512) void l34_kernel(
    const float* __restrict__ h2,
    const float* __restrict__ W3, const float* __restrict__ b3,
    const float* __restrict__ g3, const float* __restrict__ be3,
    const float* __restrict__ rm3, const float* __restrict__ rv3,
    const float* __restrict__ W4, const float* __restrict__ b4,
    float* __restrict__ out)
{
    __shared__ float hs[256];
    __shared__ float red3[4][128];
    __shared__ float h3s[128];
    __shared__ float red4[8][64];
    const int t = threadIdx.x;
    const int b = blockIdx.x;

    if (t < 256) hs[t] = h2[b * 256 + t];
    __syncthreads();

    {
        const int o  = t & 127;
        const int cg = t >> 7;
        const int kb = cg * 64;
        float acc = 0.f;
        #pragma unroll 8
        for (int kk = 0; kk < 64; ++kk)
            acc = fmaf(hs[kb + kk], W3[(size_t)(kb + kk) * 128 + o], acc);
        red3[cg][o] = acc;
    }
    __syncthreads();
    if (t < 128) {
        float dot = red3[0][t] + red3[1][t] + red3[2][t] + red3[3][t];
        const float v = (dot + b3[t] - rm3[t]) * g3[t] * rsqrtf(rv3[t] + BN_EPS) + be3[t];
        h3s[t] = v > 0.f ? v : 0.f;
    }
    __syncthreads();

    {
        const int o  = t & 63;
        const int om = (o < 40) ? o : 39;
        const int cg = t >> 6;
        const int kb = cg * 16;
        float acc = 0.f;
        #pragma unroll
        for (int kk = 0; kk < 16; ++kk)
            acc = fmaf(h3s[kb + kk], W4[(size_t)(kb + kk) * 40 + om], acc);
        red4[cg][o] = acc;
    }
    __syncthreads();
    if (t < 40) {
        float dot = 0.f;
        #pragma unroll
        for (int j = 0; j < 8; ++j) dot += red4[j][t];
        out[b * 40 + t] = dot + b4[t];
    }
}

extern "C" void kernel_launch(void* const* d_in, const int* in_sizes, int n_in,
                              void* d_out, int out_size, void* d_ws, size_t ws_size,
                              hipStream_t stream) {
    const float* x  = (const float*)d_in[0];
    const float* W1 = (const float*)d_in[2];
    const float* b1 = (const float*)d_in[3];
    const float* g1 = (const float*)d_in[4];
    const float* be1= (const float*)d_in[5];
    const float* rm1= (const float*)d_in[6];
    const float* rv1= (const float*)d_in[7];
    const float* W2 = (const float*)d_in[8];
    const float* b2 = (const float*)d_in[9];
    const float* g2 = (const float*)d_in[10];
    const float* be2= (const float*)d_in[11];
    const float* rm2= (const float*)d_in[12];
    const float* rv2= (const float*)d_in[13];
    const float* W3 = (const float*)d_in[14];
    const float* b3 = (const float*)d_in[15];
    const float* g3 = (const float*)d_in[16];
    const float* be3= (const float*)d_in[17];
    const float* rm3= (const float*)d_in[18];
    const float* rv3= (const float*)d_in[19];
    const float* W4 = (const float*)d_in[20];
    const float* b4 = (const float*)d_in[21];
    float* out = (float*)d_out;

    float* part = (float*)d_ws;                              // 32*16*815 f32
    float* h1   = part + (size_t)BATCH * NSPLIT * M_POLY;    // 32*512
    float* h2   = h1 + (size_t)BATCH * 512;                  // 32*256

    moments_kernel<<<dim3(NSPLIT, BATCH), 256, 0, stream>>>(x, part);
    l1_kernel<<<dim3(16, BATCH), 512, 0, stream>>>(part,
        W1, b1, g1, be1, rm1, rv1, h1);
    l2_kernel<<<dim3(8, BATCH), 512, 0, stream>>>(h1,
        W2, b2, g2, be2, rm2, rv2, h2);
    l34_kernel<<<BATCH, 512, 0, stream>>>(h2,
        W3, b3, g3, be3, rm3, rv3, W4, b4, out);
}